// Round 8
// baseline (760.395 us; speedup 1.0000x reference)
//
#include <hip/hip_runtime.h>
#include <hip/hip_fp16.h>
#include <math.h>

#define NN 100000
#define EE 1600000
#define GB 512
#define INC 96
#define HH 128
#define CC 100
#define MAXD 64     // max in-degree slot count (Binomial(1.6M,1e-5): P(>64) ~ e^-40)
#define BUCKB 9     // 512 nodes per bucket
#define NBUK 196    // ceil(100000/512)
#define CAPB 10240  // bucket capacity (mean 8192, sigma~90 -> +22 sigma)
#define EB 1024     // edges per k_edge_split block (1563 blocks keeps MFMA occupancy up)

typedef __bf16 bf16x8 __attribute__((ext_vector_type(8)));
typedef _Float16 f16x8 __attribute__((ext_vector_type(8)));
typedef float f32x4 __attribute__((ext_vector_type(4)));

// packed edge record: (row << 15) | (half_bits_of_RAW_weight & 0x7FFF)  -- weight > 0 so sign bit is free
// normalization dis[src]*w*dis[dst] is folded into GEMM epilogue (src) + agg epilogue (dst)
__device__ __forceinline__ float unpack_w_f32(unsigned v) {
    return __half2float(__ushort_as_half((unsigned short)(v & 0x7FFFu)));
}
__device__ __forceinline__ __half2 unpack_w_h2(unsigned v) {
    __half h = __ushort_as_half((unsigned short)(v & 0x7FFFu));
    return __halves2half2(h, h);
}

// ---------------------------------------------------------------- all weight prep in one launch
// blocks 0..287: W[K,128] f32 -> Wt[128,K] f16 for {W0,resW:K=96} {W1,W2,W3:K=128}
// block 288: build W1 MFMA B-fragments (bf16, edge MLP) + zero cntB
__global__ __launch_bounds__(512) void k_prep(
    const float* __restrict__ W0, const float* __restrict__ resW,
    const float* __restrict__ W1m, const float* __restrict__ W2m, const float* __restrict__ W3m,
    const float* __restrict__ eeW1,
    __half* __restrict__ wt0, __half* __restrict__ wtR,
    __half* __restrict__ wt1, __half* __restrict__ wt2, __half* __restrict__ wt3,
    __bf16* __restrict__ w1f, int* __restrict__ cntB)
{
    int tid = threadIdx.x;
    if (blockIdx.x == 288) {
        int t = tid >> 6, lane = tid & 63;
        int ln15 = lane & 15, quad = lane >> 4;
        bf16x8 v = {};
        if (quad == 0) {
#pragma unroll
            for (int j = 0; j < 8; ++j) v[j] = (__bf16)eeW1[j * 128 + t * 16 + ln15];
        }
        *(bf16x8*)&w1f[(size_t)(t * 64 + lane) * 8] = v;
        if (tid < NBUK) cntB[tid] = 0;
        return;
    }
    if (tid >= 256) return;
    int idx = blockIdx.x * 256 + tid;
    const float* src; __half* dst; int K, base;
    if (idx < 12288)      { src = W0;   dst = wt0; K = 96;  base = 0; }
    else if (idx < 24576) { src = resW; dst = wtR; K = 96;  base = 12288; }
    else if (idx < 40960) { src = W1m;  dst = wt1; K = 128; base = 24576; }
    else if (idx < 57344) { src = W2m;  dst = wt2; K = 128; base = 40960; }
    else if (idx < 73728) { src = W3m;  dst = wt3; K = 128; base = 57344; }
    else return;
    int l = idx - base;
    int k = l >> 7, n = l & 127;
    dst[(size_t)n * K + k] = __float2half(src[l]);
}

// ---------------------------------------------------------------- FUSED edge MLP (MFMA) + bucket multi-split
// per block: 8 MFMA tiles of 128 edges -> weights in LDS; LDS histogram; one global
// atomic per (block,bucket); scatter into bucket arrays. No ew round-trip, one launch.
__global__ __launch_bounds__(256) void k_edge_split(
    const float* __restrict__ ea,
    const __bf16* __restrict__ w1f, const float* __restrict__ b1,
    const float* __restrict__ W2, const float* __restrict__ b2,
    const int* __restrict__ ei, int* __restrict__ cntB, uint2* __restrict__ barr)
{
    __shared__ float sDot[128];
    __shared__ __half ewbuf[EB];
    __shared__ unsigned hist[NBUK];
    __shared__ unsigned cur[NBUK];
    int tid = threadIdx.x, wva = tid >> 6, lane = tid & 63;
    int ln15 = lane & 15, quad = lane >> 4;
    for (int b = tid; b < NBUK; b += 256) hist[b] = 0;

    bf16x8 bfr[8];
#pragma unroll
    for (int t = 0; t < 8; ++t) bfr[t] = *(const bf16x8*)&w1f[(size_t)(t * 64 + lane) * 8];
    __syncthreads();

    int e0 = blockIdx.x * EB;
#pragma unroll 1
    for (int tile = 0; tile < EB / 128; ++tile) {
        int tbase = e0 + tile * 128;
        if (tbase < EE) {
            int eb2 = tbase + wva * 32;
            bf16x8 a0 = {}, a1 = {};
            if (quad == 0) {
                const float* p0 = &ea[(size_t)(eb2 + ln15) * 8];
                float4 u0 = *(const float4*)p0, u1 = *(const float4*)(p0 + 4);
                a0[0] = (__bf16)u0.x; a0[1] = (__bf16)u0.y; a0[2] = (__bf16)u0.z; a0[3] = (__bf16)u0.w;
                a0[4] = (__bf16)u1.x; a0[5] = (__bf16)u1.y; a0[6] = (__bf16)u1.z; a0[7] = (__bf16)u1.w;
                const float* p1 = &ea[(size_t)(eb2 + 16 + ln15) * 8];
                float4 w0 = *(const float4*)p1, w1v = *(const float4*)(p1 + 4);
                a1[0] = (__bf16)w0.x; a1[1] = (__bf16)w0.y; a1[2] = (__bf16)w0.z; a1[3] = (__bf16)w0.w;
                a1[4] = (__bf16)w1v.x; a1[5] = (__bf16)w1v.y; a1[6] = (__bf16)w1v.z; a1[7] = (__bf16)w1v.w;
            }
            f32x4 d0 = {0.f, 0.f, 0.f, 0.f}, d1 = {0.f, 0.f, 0.f, 0.f};
#pragma unroll
            for (int t = 0; t < 8; ++t) {
                f32x4 z = {0.f, 0.f, 0.f, 0.f};
                f32x4 c0 = __builtin_amdgcn_mfma_f32_16x16x32_bf16(a0, bfr[t], z, 0, 0, 0);
                f32x4 c1 = __builtin_amdgcn_mfma_f32_16x16x32_bf16(a1, bfr[t], z, 0, 0, 0);
                int col = t * 16 + ln15;
                float b1v = b1[col], w2v = W2[col];
#pragma unroll
                for (int r = 0; r < 4; ++r) {
                    float v0 = fmaxf(c0[r] + b1v, 0.0f);
                    float v1 = fmaxf(c1[r] + b1v, 0.0f);
                    d0[r] = fmaf(v0, w2v, d0[r]);
                    d1[r] = fmaf(v1, w2v, d1[r]);
                }
            }
#pragma unroll
            for (int o = 1; o < 16; o <<= 1) {
#pragma unroll
                for (int r = 0; r < 4; ++r) {
                    d0[r] += __shfl_xor(d0[r], o, 64);
                    d1[r] += __shfl_xor(d1[r], o, 64);
                }
            }
            if (ln15 == 0) {
#pragma unroll
                for (int r = 0; r < 4; ++r) {
                    sDot[wva * 32 + quad * 4 + r]      = d0[r];
                    sDot[wva * 32 + 16 + quad * 4 + r] = d1[r];
                }
            }
            __syncthreads();
            if (tid < 128) {
                int e = tbase + tid;
                float xv = sDot[tid] + b2[0];
                float sp = (xv > 20.0f) ? xv : log1pf(expf(xv));
                ewbuf[tile * 128 + tid] = __float2half(sp + 1e-4f);
                atomicAdd(&hist[ei[EE + e] >> BUCKB], 1u);
            }
        }
        __syncthreads();                       // protect sDot reuse across tiles
    }
    // reserve global base per bucket; cur doubles as the write cursor
    for (int b = tid; b < NBUK; b += 256)
        cur[b] = (hist[b] > 0) ? (unsigned)atomicAdd(&cntB[b], (int)hist[b]) : 0u;
    __syncthreads();
#pragma unroll
    for (int j = 0; j < EB / 256; ++j) {
        int e = e0 + j * 256 + tid;
        if (e < EE) {
            int c = ei[EE + e];                // L2-hot re-read
            int b = c >> BUCKB;
            unsigned pos = atomicAdd(&cur[b], 1u);
            if (pos < CAPB) {
                unsigned hb = (unsigned)__half_as_ushort(ewbuf[j * 256 + tid]) & 0x7FFFu;
                barr[(size_t)b * CAPB + pos] = make_uint2(((unsigned)c << 15) | hb, (unsigned)ei[e]);
            }
        }
    }
}

// ---------------------------------------------------------------- phase B: bucket -> fixed-stride CSR
// ranks via LDS atomics (zero global atomics); folds deg/dis computation
__global__ __launch_bounds__(256) void k_build(const int* __restrict__ cntB, const uint2* __restrict__ barr,
                                               unsigned* __restrict__ epack, int* __restrict__ cnt,
                                               float* __restrict__ dis) {
    __shared__ unsigned ncnt[512];
    __shared__ float ndeg[512];
    int tid = threadIdx.x, b = blockIdx.x;
    for (int i = tid; i < 512; i += 256) { ncnt[i] = 0; ndeg[i] = 0.0f; }
    __syncthreads();
    int n0 = b << BUCKB;
    int m = cntB[b]; if (m > CAPB) m = CAPB;
    for (int i = tid; i < m; i += 256) {
        uint2 rec = barr[(size_t)b * CAPB + i];
        int c = (int)(rec.x >> 15);
        int cl = c - n0;
        unsigned rank = atomicAdd(&ncnt[cl], 1u);
        if (rank < MAXD) epack[(size_t)c * MAXD + rank] = (rec.y << 15) | (rec.x & 0x7FFFu);
        atomicAdd(&ndeg[cl], unpack_w_f32(rec.x));
    }
    __syncthreads();
    int nn = NN - n0; if (nn > 512) nn = 512;
    for (int i = tid; i < nn; i += 256) {
        unsigned cc = ncnt[i]; if (cc > MAXD) cc = MAXD;
        cnt[n0 + i] = (int)cc;
        dis[n0 + i] = rsqrtf(1.0f + ndeg[i]);
    }
}

// ---------------------------------------------------------------- f16 MFMA GEMM, LDS-free: C[M,128] = dis[row] * (A[M,K]@Bt^T)
__global__ __launch_bounds__(256) void k_gemm_f16(
    const __half* __restrict__ A, const __half* __restrict__ Bt,
    const float* __restrict__ dis, __half* __restrict__ C, int M, int K)
{
    int tid = threadIdx.x;
    int wv = tid >> 6, lane = tid & 63;
    int ln15 = lane & 15, quad = lane >> 4;
    int m0 = blockIdx.x * 64;
    int n0 = wv * 32;
    f32x4 acc[4][2];
#pragma unroll
    for (int mt = 0; mt < 4; ++mt)
#pragma unroll
        for (int nt = 0; nt < 2; ++nt) acc[mt][nt] = (f32x4){0.f, 0.f, 0.f, 0.f};

    int rowm[4];
#pragma unroll
    for (int mt = 0; mt < 4; ++mt) {
        int r = m0 + mt * 16 + ln15;
        rowm[mt] = r < M ? r : M - 1;
    }
    for (int kc = 0; kc < K; kc += 32) {
        f16x8 af[4], bfr[2];
#pragma unroll
        for (int mt = 0; mt < 4; ++mt)
            af[mt] = *(const f16x8*)&A[(size_t)rowm[mt] * K + kc + quad * 8];
#pragma unroll
        for (int nt = 0; nt < 2; ++nt)
            bfr[nt] = *(const f16x8*)&Bt[(size_t)(n0 + nt * 16 + ln15) * K + kc + quad * 8];
#pragma unroll
        for (int mt = 0; mt < 4; ++mt)
#pragma unroll
            for (int nt = 0; nt < 2; ++nt)
                acc[mt][nt] = __builtin_amdgcn_mfma_f32_16x16x32_f16(af[mt], bfr[nt], acc[mt][nt], 0, 0, 0);
    }
#pragma unroll
    for (int nt = 0; nt < 2; ++nt) {
        int col = n0 + nt * 16 + ln15;
#pragma unroll
        for (int mt = 0; mt < 4; ++mt) {
#pragma unroll
            for (int r = 0; r < 4; ++r) {
                int row = m0 + mt * 16 + quad * 4 + r;
                if (row < M) C[(size_t)row * 128 + col] = __float2half(acc[mt][nt][r] * dis[row]);
            }
        }
    }
}

// ---------------------------------------------------------------- dual-B GEMM for layer 0, fp32 A (no cast kernel):
// C1 = dis[row] * (A@Bt1^T), C2 = A@Bt2^T + bias2 -- shares A loads (one pass over x)
__global__ __launch_bounds__(256) void k_gemm_dual(
    const float* __restrict__ A, const __half* __restrict__ Bt1, const __half* __restrict__ Bt2,
    const float* __restrict__ bias2, const float* __restrict__ dis,
    __half* __restrict__ C1, __half* __restrict__ C2, int M, int K)
{
    int tid = threadIdx.x;
    int wv = tid >> 6, lane = tid & 63;
    int ln15 = lane & 15, quad = lane >> 4;
    int m0 = blockIdx.x * 64;
    int n0 = wv * 32;
    f32x4 acc1[4][2], acc2[4][2];
#pragma unroll
    for (int mt = 0; mt < 4; ++mt)
#pragma unroll
        for (int nt = 0; nt < 2; ++nt) {
            acc1[mt][nt] = (f32x4){0.f, 0.f, 0.f, 0.f};
            acc2[mt][nt] = (f32x4){0.f, 0.f, 0.f, 0.f};
        }
    int rowm[4];
#pragma unroll
    for (int mt = 0; mt < 4; ++mt) {
        int r = m0 + mt * 16 + ln15;
        rowm[mt] = r < M ? r : M - 1;
    }
    for (int kc = 0; kc < K; kc += 32) {
        f16x8 af[4], bf1[2], bf2[2];
#pragma unroll
        for (int mt = 0; mt < 4; ++mt) {
            const float* ap = &A[(size_t)rowm[mt] * K + kc + quad * 8];
            float4 u0 = *(const float4*)ap, u1 = *(const float4*)(ap + 4);
            af[mt][0] = (_Float16)u0.x; af[mt][1] = (_Float16)u0.y;
            af[mt][2] = (_Float16)u0.z; af[mt][3] = (_Float16)u0.w;
            af[mt][4] = (_Float16)u1.x; af[mt][5] = (_Float16)u1.y;
            af[mt][6] = (_Float16)u1.z; af[mt][7] = (_Float16)u1.w;
        }
#pragma unroll
        for (int nt = 0; nt < 2; ++nt) {
            bf1[nt] = *(const f16x8*)&Bt1[(size_t)(n0 + nt * 16 + ln15) * K + kc + quad * 8];
            bf2[nt] = *(const f16x8*)&Bt2[(size_t)(n0 + nt * 16 + ln15) * K + kc + quad * 8];
        }
#pragma unroll
        for (int mt = 0; mt < 4; ++mt)
#pragma unroll
            for (int nt = 0; nt < 2; ++nt) {
                acc1[mt][nt] = __builtin_amdgcn_mfma_f32_16x16x32_f16(af[mt], bf1[nt], acc1[mt][nt], 0, 0, 0);
                acc2[mt][nt] = __builtin_amdgcn_mfma_f32_16x16x32_f16(af[mt], bf2[nt], acc2[mt][nt], 0, 0, 0);
            }
    }
#pragma unroll
    for (int nt = 0; nt < 2; ++nt) {
        int col = n0 + nt * 16 + ln15;
        float bv2 = bias2[col];
#pragma unroll
        for (int mt = 0; mt < 4; ++mt) {
#pragma unroll
            for (int r = 0; r < 4; ++r) {
                int row = m0 + mt * 16 + quad * 4 + r;
                if (row < M) {
                    C1[(size_t)row * 128 + col] = __float2half(acc1[mt][nt][r] * dis[row]);
                    C2[(size_t)row * 128 + col] = __float2half(acc2[mt][nt][r] + bv2);
                }
            }
        }
    }
}

// ---------------------------------------------------------------- aggregate + bias + LN + residual + relu (f16 pk-fma)
// hw rows are pre-scaled by dis[src]; raw weights in epack; dst scale applied once at epilogue.
__global__ __launch_bounds__(256) void k_agg_ln(
    const __half* __restrict__ hw, const float* __restrict__ dis,
    const int* __restrict__ cnt, const unsigned* __restrict__ epack,
    const float* __restrict__ cb, const float* __restrict__ gam,
    const float* __restrict__ bet, const __half* __restrict__ res,
    __half* __restrict__ out, int n)
{
    int wv = threadIdx.x >> 6;
    int lane = threadIdx.x & 63;
    int i = blockIdx.x * 4 + wv;
    if (i >= n) return;
    float di = dis[i];
    __half2 acca = *(const __half2*)&hw[(size_t)i * HH + lane * 2];  // self-loop, weight 1
    __half2 accb = __halves2half2(__float2half(0.0f), __float2half(0.0f));
    int cn = cnt[i];
    const unsigned* ebase = &epack[(size_t)i * MAXD];    // 256B-aligned per node
    int k = 0;
    for (; k + 8 <= cn; k += 8) {
        uint4 q0 = *(const uint4*)&ebase[k];      // 4 edges
        uint4 q1 = *(const uint4*)&ebase[k + 4];  // 4 edges
        __half2 v0 = *(const __half2*)&hw[(size_t)(q0.x >> 15) * HH + lane * 2];
        __half2 v1 = *(const __half2*)&hw[(size_t)(q0.y >> 15) * HH + lane * 2];
        __half2 v2 = *(const __half2*)&hw[(size_t)(q0.z >> 15) * HH + lane * 2];
        __half2 v3 = *(const __half2*)&hw[(size_t)(q0.w >> 15) * HH + lane * 2];
        __half2 v4 = *(const __half2*)&hw[(size_t)(q1.x >> 15) * HH + lane * 2];
        __half2 v5 = *(const __half2*)&hw[(size_t)(q1.y >> 15) * HH + lane * 2];
        __half2 v6 = *(const __half2*)&hw[(size_t)(q1.z >> 15) * HH + lane * 2];
        __half2 v7 = *(const __half2*)&hw[(size_t)(q1.w >> 15) * HH + lane * 2];
        acca = __hfma2(v0, unpack_w_h2(q0.x), acca);
        accb = __hfma2(v4, unpack_w_h2(q1.x), accb);
        acca = __hfma2(v1, unpack_w_h2(q0.y), acca);
        accb = __hfma2(v5, unpack_w_h2(q1.y), accb);
        acca = __hfma2(v2, unpack_w_h2(q0.z), acca);
        accb = __hfma2(v6, unpack_w_h2(q1.z), accb);
        acca = __hfma2(v3, unpack_w_h2(q0.w), acca);
        accb = __hfma2(v7, unpack_w_h2(q1.w), accb);
    }
    for (; k < cn; ++k) {
        unsigned e = ebase[k];
        __half2 v = *(const __half2*)&hw[(size_t)(e >> 15) * HH + lane * 2];
        acca = __hfma2(v, unpack_w_h2(e), acca);
    }
    __half2 acc = __hadd2(acca, accb);
    float2 af = __half22float2(acc);
    float2 cbv = *(const float2*)&cb[lane * 2];
    af.x = fmaf(di, af.x, cbv.x);          // dst-side normalization + conv bias
    af.y = fmaf(di, af.y, cbv.y);
    // LayerNorm over 128 via wave reduction
    float s1 = af.x + af.y;
    float s2 = af.x * af.x + af.y * af.y;
#pragma unroll
    for (int o = 32; o > 0; o >>= 1) {
        s1 += __shfl_xor(s1, o, 64);
        s2 += __shfl_xor(s2, o, 64);
    }
    float mean = s1 * (1.0f / HH);
    float var = fmaxf(s2 * (1.0f / HH) - mean * mean, 0.0f);
    float rstd = rsqrtf(var + 1e-5f);
    float2 gv = *(const float2*)&gam[lane * 2];
    float2 bv = *(const float2*)&bet[lane * 2];
    float2 rv = __half22float2(*(const __half2*)&res[(size_t)i * HH + lane * 2]);
    float hx = fmaxf(fmaf(gv.x, (af.x - mean) * rstd, bv.x) + rv.x, 0.0f);
    float hy = fmaxf(fmaf(gv.y, (af.y - mean) * rstd, bv.y) + rv.y, 0.0f);
    *(__half2*)&out[(size_t)i * HH + lane * 2] = __floats2half2_rn(hx, hy);
}

// ---------------------------------------------------------------- fused mean/max pool + head (per graph)
__global__ __launch_bounds__(512) void k_pool_head(
    const __half* __restrict__ l0, const __half* __restrict__ l1,
    const __half* __restrict__ l2, const __half* __restrict__ l3,
    const int* __restrict__ batch,
    const float* __restrict__ hW1, const float* __restrict__ hb1,
    const float* __restrict__ hW2, const float* __restrict__ hb2,
    float* __restrict__ out, int n)
{
    __shared__ float ssum[8][128];
    __shared__ float smax[8][128];
    __shared__ __align__(16) float sg[256];
    __shared__ __align__(16) float sh[128];
    int g = blockIdx.x, tid = threadIdx.x;
    int grp = tid >> 6, lane = tid & 63;
    int lo = 0, hi = n;
    while (lo < hi) { int m = (lo + hi) >> 1; if (batch[m] < g) lo = m + 1; else hi = m; }
    int start = lo;
    lo = start; hi = n;
    while (lo < hi) { int m = (lo + hi) >> 1; if (batch[m] < g + 1) lo = m + 1; else hi = m; }
    int end = lo;
    float sx = 0.0f, sy = 0.0f, mx = -INFINITY, my = -INFINITY;
    for (int nd = start + grp; nd < end; nd += 8) {
        size_t off = (size_t)nd * HH + lane * 2;
        float2 v0 = __half22float2(*(const __half2*)&l0[off]);
        float2 v1 = __half22float2(*(const __half2*)&l1[off]);
        float2 v2 = __half22float2(*(const __half2*)&l2[off]);
        float2 v3 = __half22float2(*(const __half2*)&l3[off]);
        float vx = (v0.x + v1.x + v2.x + v3.x) * 0.25f;
        float vy = (v0.y + v1.y + v2.y + v3.y) * 0.25f;
        sx += vx; sy += vy;
        mx = fmaxf(mx, vx); my = fmaxf(my, vy);
    }
    ssum[grp][lane * 2] = sx; ssum[grp][lane * 2 + 1] = sy;
    smax[grp][lane * 2] = mx; smax[grp][lane * 2 + 1] = my;
    __syncthreads();
    if (tid < 128) {
        float s = 0.0f, m = -INFINITY;
#pragma unroll
        for (int j = 0; j < 8; ++j) {
            s += ssum[j][tid];
            m = fmaxf(m, smax[j][tid]);
        }
        int cntg = end - start;
        sg[tid] = s / fmaxf((float)cntg, 1.0f);
        sg[128 + tid] = (cntg > 0) ? m : 0.0f;
    }
    __syncthreads();
    if (tid < 128) {
        float h = hb1[tid];
        for (int k = 0; k < 256; ++k) h = fmaf(sg[k], hW1[(size_t)k * 128 + tid], h);
        sh[tid] = fmaxf(h, 0.0f);
    }
    __syncthreads();
    if (tid < 100) {
        float o = hb2[tid];
        for (int k = 0; k < 128; ++k) o = fmaf(sh[k], hW2[(size_t)k * 100 + tid], o);
        out[(size_t)g * 100 + tid] = o;
    }
}

// ---------------------------------------------------------------- launch
extern "C" void kernel_launch(void* const* d_in, const int* in_sizes, int n_in,
                              void* d_out, int out_size, void* d_ws, size_t ws_size,
                              hipStream_t stream) {
    const float* x     = (const float*)d_in[0];
    const int*   ei    = (const int*)d_in[1];
    const int*   batch = (const int*)d_in[2];
    const float* ea    = (const float*)d_in[3];
    const float* eeW1  = (const float*)d_in[4];
    const float* eeb1  = (const float*)d_in[5];
    const float* eeW2  = (const float*)d_in[6];
    const float* eeb2  = (const float*)d_in[7];
    const float* W[4]  = {(const float*)d_in[8], (const float*)d_in[10], (const float*)d_in[12], (const float*)d_in[14]};
    const float* cb[4] = {(const float*)d_in[9], (const float*)d_in[11], (const float*)d_in[13], (const float*)d_in[15]};
    const float* gm[4] = {(const float*)d_in[16], (const float*)d_in[18], (const float*)d_in[20], (const float*)d_in[22]};
    const float* be[4] = {(const float*)d_in[17], (const float*)d_in[19], (const float*)d_in[21], (const float*)d_in[23]};
    const float* resW  = (const float*)d_in[24];
    const float* resb  = (const float*)d_in[25];
    const float* hW1   = (const float*)d_in[26];
    const float* hb1   = (const float*)d_in[27];
    const float* hW2   = (const float*)d_in[28];
    const float* hb2   = (const float*)d_in[29];
    float* out = (float*)d_out;

    // workspace layout (~172 MB)
    char* w = (char*)d_ws;
    auto alloc = [&](size_t bytes) { void* p = w; w += (bytes + 255) & ~(size_t)255; return p; };
    float*    dis    = (float*)   alloc((size_t)NN * 4);                 //  0.4 MB
    int*      cnt    = (int*)     alloc((size_t)NN * 4);                 //  0.4 MB
    int*      cntB   = (int*)     alloc((size_t)NBUK * 4);               //  0.8 KB
    uint2*    barr   = (uint2*)   alloc((size_t)NBUK * CAPB * 8);        // 16.1 MB bucket arrays
    unsigned* epack  = (unsigned*)alloc((size_t)(NN * MAXD + 64) * 4);   // 25.6 MB packed CSR (+overread pad)
    __half*   hw     = (__half*)  alloc((size_t)NN * HH * 2);            // 25.6 MB
    __half*   lout[4];
    for (int i = 0; i < 4; ++i) lout[i] = (__half*)alloc((size_t)NN * HH * 2);  // 4 x 25.6 MB
    __half*   wt0    = (__half*)  alloc((size_t)INC * HH * 2);
    __half*   wtR    = (__half*)  alloc((size_t)INC * HH * 2);
    __half*   wt1    = (__half*)  alloc((size_t)HH * HH * 2);
    __half*   wt2    = (__half*)  alloc((size_t)HH * HH * 2);
    __half*   wt3    = (__half*)  alloc((size_t)HH * HH * 2);
    __bf16*   w1f    = (__bf16*)  alloc((size_t)8 * 64 * 8 * 2);         // 8 KB MFMA B-frags for edge MLP
    __half*   wtc[4] = {wt0, wt1, wt2, wt3};
    __half*   res0   = lout[1];   // alias: res0 dead after layer-0 agg; lout[1] written at layer-1 agg

    int nblkEdge = (EE + EB - 1) / EB;       // 1563
    int nblkGemm = (NN + 63) / 64;           // 1563

    k_prep<<<289, 512, 0, stream>>>(W[0], resW, W[1], W[2], W[3], eeW1,
                                    wt0, wtR, wt1, wt2, wt3, w1f, cntB);
    k_edge_split<<<nblkEdge, 256, 0, stream>>>(ea, w1f, eeb1, eeW2, eeb2, ei, cntB, barr);
    k_build<<<NBUK, 256, 0, stream>>>(cntB, barr, epack, cnt, dis);

    // layer 0 (K=96, fp32 A): hw = dis .* (x@W0); res0 = x@res_W + res_b  (one pass over x)
    k_gemm_dual<<<nblkGemm, 256, 0, stream>>>(x, wt0, wtR, resb, dis, hw, res0, NN, INC);
    k_agg_ln<<<(NN + 3) / 4, 256, 0, stream>>>(hw, dis, cnt, epack,
                                               cb[0], gm[0], be[0], res0, lout[0], NN);
    // layers 1..3
    for (int l = 1; l < 4; ++l) {
        k_gemm_f16<<<nblkGemm, 256, 0, stream>>>(lout[l - 1], wtc[l], dis, hw, NN, HH);
        k_agg_ln<<<(NN + 3) / 4, 256, 0, stream>>>(hw, dis, cnt, epack,
                                                   cb[l], gm[l], be[l], lout[l - 1], lout[l], NN);
    }

    k_pool_head<<<GB, 512, 0, stream>>>(lout[0], lout[1], lout[2], lout[3], batch,
                                        hW1, hb1, hW2, hb2, out, NN);
}

// Round 9
// 747.792 us; speedup vs baseline: 1.0169x; 1.0169x over previous
//
#include <hip/hip_runtime.h>
#include <hip/hip_fp16.h>
#include <math.h>

#define NN 100000
#define EE 1600000
#define GB 512
#define INC 96
#define HH 128
#define CC 100
#define MAXD 64     // max in-degree slot count (Binomial(1.6M,1e-5): P(>64) ~ e^-40)
#define BUCKB 9     // 512 nodes per bucket
#define NBUK 196    // ceil(100000/512)
#define CAPB 10240  // bucket capacity (mean 8192, sigma~90 -> +22 sigma)
#define EB 4096     // edges per k_split block

typedef __bf16 bf16x8 __attribute__((ext_vector_type(8)));
typedef _Float16 f16x8 __attribute__((ext_vector_type(8)));
typedef float f32x4 __attribute__((ext_vector_type(4)));

// packed edge record: (row << 15) | (half_bits_of_RAW_weight & 0x7FFF)  -- weight > 0 so sign bit is free
// normalization dis[src]*w*dis[dst] is folded into GEMM epilogue (src) + agg epilogue (dst)
__device__ __forceinline__ float unpack_w_f32(unsigned v) {
    return __half2float(__ushort_as_half((unsigned short)(v & 0x7FFFu)));
}
__device__ __forceinline__ __half2 unpack_w_h2(unsigned v) {
    __half h = __ushort_as_half((unsigned short)(v & 0x7FFFu));
    return __halves2half2(h, h);
}

// ---------------------------------------------------------------- all weight prep in one launch
// blocks 0..287: W[K,128] f32 -> Wt[128,K] f16 for {W0,resW:K=96} {W1,W2,W3:K=128}
// block 288: build W1 MFMA B-fragments (bf16, edge MLP) + zero cntB
__global__ __launch_bounds__(512) void k_prep(
    const float* __restrict__ W0, const float* __restrict__ resW,
    const float* __restrict__ W1m, const float* __restrict__ W2m, const float* __restrict__ W3m,
    const float* __restrict__ eeW1,
    __half* __restrict__ wt0, __half* __restrict__ wtR,
    __half* __restrict__ wt1, __half* __restrict__ wt2, __half* __restrict__ wt3,
    __bf16* __restrict__ w1f, int* __restrict__ cntB)
{
    int tid = threadIdx.x;
    if (blockIdx.x == 288) {
        int t = tid >> 6, lane = tid & 63;
        int ln15 = lane & 15, quad = lane >> 4;
        bf16x8 v = {};
        if (quad == 0) {
#pragma unroll
            for (int j = 0; j < 8; ++j) v[j] = (__bf16)eeW1[j * 128 + t * 16 + ln15];
        }
        *(bf16x8*)&w1f[(size_t)(t * 64 + lane) * 8] = v;
        if (tid < NBUK) cntB[tid] = 0;
        return;
    }
    if (tid >= 256) return;
    int idx = blockIdx.x * 256 + tid;
    const float* src; __half* dst; int K, base;
    if (idx < 12288)      { src = W0;   dst = wt0; K = 96;  base = 0; }
    else if (idx < 24576) { src = resW; dst = wtR; K = 96;  base = 12288; }
    else if (idx < 40960) { src = W1m;  dst = wt1; K = 128; base = 24576; }
    else if (idx < 57344) { src = W2m;  dst = wt2; K = 128; base = 40960; }
    else if (idx < 73728) { src = W3m;  dst = wt3; K = 128; base = 57344; }
    else return;
    int l = idx - base;
    int k = l >> 7, n = l & 127;
    dst[(size_t)n * K + k] = __float2half(src[l]);
}

// ---------------------------------------------------------------- edge MLP via MFMA (pure streaming, no atomics)
__global__ __launch_bounds__(256) void k_edge_mlp_mfma(
    const float* __restrict__ ea,
    const __bf16* __restrict__ w1f, const float* __restrict__ b1,
    const float* __restrict__ W2, const float* __restrict__ b2,
    __half* __restrict__ ew)
{
    __shared__ float sDot[128];
    int tid = threadIdx.x, wva = tid >> 6, lane = tid & 63;
    int ln15 = lane & 15, quad = lane >> 4;
    int ebase = blockIdx.x * 128 + wva * 32;

    bf16x8 bfr[8];
#pragma unroll
    for (int t = 0; t < 8; ++t) bfr[t] = *(const bf16x8*)&w1f[(size_t)(t * 64 + lane) * 8];

    bf16x8 a0 = {}, a1 = {};
    if (quad == 0) {
        const float* p0 = &ea[(size_t)(ebase + ln15) * 8];
        float4 u0 = *(const float4*)p0, u1 = *(const float4*)(p0 + 4);
        a0[0] = (__bf16)u0.x; a0[1] = (__bf16)u0.y; a0[2] = (__bf16)u0.z; a0[3] = (__bf16)u0.w;
        a0[4] = (__bf16)u1.x; a0[5] = (__bf16)u1.y; a0[6] = (__bf16)u1.z; a0[7] = (__bf16)u1.w;
        const float* p1 = &ea[(size_t)(ebase + 16 + ln15) * 8];
        float4 w0 = *(const float4*)p1, w1v = *(const float4*)(p1 + 4);
        a1[0] = (__bf16)w0.x; a1[1] = (__bf16)w0.y; a1[2] = (__bf16)w0.z; a1[3] = (__bf16)w0.w;
        a1[4] = (__bf16)w1v.x; a1[5] = (__bf16)w1v.y; a1[6] = (__bf16)w1v.z; a1[7] = (__bf16)w1v.w;
    }

    f32x4 d0 = {0.f, 0.f, 0.f, 0.f}, d1 = {0.f, 0.f, 0.f, 0.f};
#pragma unroll
    for (int t = 0; t < 8; ++t) {
        f32x4 z = {0.f, 0.f, 0.f, 0.f};
        f32x4 c0 = __builtin_amdgcn_mfma_f32_16x16x32_bf16(a0, bfr[t], z, 0, 0, 0);
        f32x4 c1 = __builtin_amdgcn_mfma_f32_16x16x32_bf16(a1, bfr[t], z, 0, 0, 0);
        int col = t * 16 + ln15;
        float b1v = b1[col], w2v = W2[col];
#pragma unroll
        for (int r = 0; r < 4; ++r) {
            float v0 = fmaxf(c0[r] + b1v, 0.0f);
            float v1 = fmaxf(c1[r] + b1v, 0.0f);
            d0[r] = fmaf(v0, w2v, d0[r]);
            d1[r] = fmaf(v1, w2v, d1[r]);
        }
    }
#pragma unroll
    for (int o = 1; o < 16; o <<= 1) {
#pragma unroll
        for (int r = 0; r < 4; ++r) {
            d0[r] += __shfl_xor(d0[r], o, 64);
            d1[r] += __shfl_xor(d1[r], o, 64);
        }
    }
    if (ln15 == 0) {
#pragma unroll
        for (int r = 0; r < 4; ++r) {
            sDot[wva * 32 + quad * 4 + r]      = d0[r];
            sDot[wva * 32 + 16 + quad * 4 + r] = d1[r];
        }
    }
    __syncthreads();
    if (tid < 128) {
        int e = blockIdx.x * 128 + tid;
        float x = sDot[tid] + b2[0];
        float sp = (x > 20.0f) ? x : log1pf(expf(x));
        ew[e] = __float2half(sp + 1e-4f);
    }
}

// ---------------------------------------------------------------- phase A: bucket multi-split
// one global atomic per (block,bucket) instead of per edge (20x fewer atomics)
__global__ __launch_bounds__(256) void k_split(const int* __restrict__ ei, const __half* __restrict__ ew,
                                               int* __restrict__ cntB, uint2* __restrict__ barr) {
    __shared__ unsigned hist[NBUK];
    __shared__ unsigned gbase[NBUK];
    __shared__ unsigned short rloc[EB];
    int tid = threadIdx.x;
    for (int b = tid; b < NBUK; b += 256) hist[b] = 0;
    __syncthreads();
    int e0 = blockIdx.x * EB;
#pragma unroll
    for (int j = 0; j < EB / 256; ++j) {
        int e = e0 + j * 256 + tid;
        if (e < EE) {
            int c = ei[EE + e];
            rloc[j * 256 + tid] = (unsigned short)atomicAdd(&hist[c >> BUCKB], 1u);
        }
    }
    __syncthreads();
    for (int b = tid; b < NBUK; b += 256)
        gbase[b] = (hist[b] > 0) ? (unsigned)atomicAdd(&cntB[b], (int)hist[b]) : 0u;
    __syncthreads();
#pragma unroll
    for (int j = 0; j < EB / 256; ++j) {
        int e = e0 + j * 256 + tid;
        if (e < EE) {
            int c = ei[EE + e];
            int b = c >> BUCKB;
            unsigned pos = gbase[b] + rloc[j * 256 + tid];
            if (pos < CAPB) {
                unsigned hb = (unsigned)__half_as_ushort(ew[e]) & 0x7FFFu;
                barr[(size_t)b * CAPB + pos] = make_uint2(((unsigned)c << 15) | hb, (unsigned)ei[e]);
            }
        }
    }
}

// ---------------------------------------------------------------- phase B: bucket -> fixed-stride CSR
// ranks via LDS atomics (zero global atomics); folds deg/dis computation
__global__ __launch_bounds__(256) void k_build(const int* __restrict__ cntB, const uint2* __restrict__ barr,
                                               unsigned* __restrict__ epack, int* __restrict__ cnt,
                                               float* __restrict__ dis) {
    __shared__ unsigned ncnt[512];
    __shared__ float ndeg[512];
    int tid = threadIdx.x, b = blockIdx.x;
    for (int i = tid; i < 512; i += 256) { ncnt[i] = 0; ndeg[i] = 0.0f; }
    __syncthreads();
    int n0 = b << BUCKB;
    int m = cntB[b]; if (m > CAPB) m = CAPB;
    for (int i = tid; i < m; i += 256) {
        uint2 rec = barr[(size_t)b * CAPB + i];
        int c = (int)(rec.x >> 15);
        int cl = c - n0;
        unsigned rank = atomicAdd(&ncnt[cl], 1u);
        if (rank < MAXD) epack[(size_t)c * MAXD + rank] = (rec.y << 15) | (rec.x & 0x7FFFu);
        atomicAdd(&ndeg[cl], unpack_w_f32(rec.x));
    }
    __syncthreads();
    int nn = NN - n0; if (nn > 512) nn = 512;
    for (int i = tid; i < nn; i += 256) {
        unsigned cc = ncnt[i]; if (cc > MAXD) cc = MAXD;
        cnt[n0 + i] = (int)cc;
        dis[n0 + i] = rsqrtf(1.0f + ndeg[i]);
    }
}

// ---------------------------------------------------------------- f16 MFMA GEMM, LDS-free: C[M,128] = dis[row] * (A[M,K]@Bt^T)
__global__ __launch_bounds__(256) void k_gemm_f16(
    const __half* __restrict__ A, const __half* __restrict__ Bt,
    const float* __restrict__ dis, __half* __restrict__ C, int M, int K)
{
    int tid = threadIdx.x;
    int wv = tid >> 6, lane = tid & 63;
    int ln15 = lane & 15, quad = lane >> 4;
    int m0 = blockIdx.x * 64;
    int n0 = wv * 32;
    f32x4 acc[4][2];
#pragma unroll
    for (int mt = 0; mt < 4; ++mt)
#pragma unroll
        for (int nt = 0; nt < 2; ++nt) acc[mt][nt] = (f32x4){0.f, 0.f, 0.f, 0.f};

    int rowm[4];
#pragma unroll
    for (int mt = 0; mt < 4; ++mt) {
        int r = m0 + mt * 16 + ln15;
        rowm[mt] = r < M ? r : M - 1;
    }
    for (int kc = 0; kc < K; kc += 32) {
        f16x8 af[4], bfr[2];
#pragma unroll
        for (int mt = 0; mt < 4; ++mt)
            af[mt] = *(const f16x8*)&A[(size_t)rowm[mt] * K + kc + quad * 8];
#pragma unroll
        for (int nt = 0; nt < 2; ++nt)
            bfr[nt] = *(const f16x8*)&Bt[(size_t)(n0 + nt * 16 + ln15) * K + kc + quad * 8];
#pragma unroll
        for (int mt = 0; mt < 4; ++mt)
#pragma unroll
            for (int nt = 0; nt < 2; ++nt)
                acc[mt][nt] = __builtin_amdgcn_mfma_f32_16x16x32_f16(af[mt], bfr[nt], acc[mt][nt], 0, 0, 0);
    }
#pragma unroll
    for (int nt = 0; nt < 2; ++nt) {
        int col = n0 + nt * 16 + ln15;
#pragma unroll
        for (int mt = 0; mt < 4; ++mt) {
#pragma unroll
            for (int r = 0; r < 4; ++r) {
                int row = m0 + mt * 16 + quad * 4 + r;
                if (row < M) C[(size_t)row * 128 + col] = __float2half(acc[mt][nt][r] * dis[row]);
            }
        }
    }
}

// ---------------------------------------------------------------- dual-B GEMM for layer 0, fp32 A (no cast kernel):
// C1 = dis[row] * (A@Bt1^T), C2 = A@Bt2^T + bias2 -- shares A loads (one pass over x)
__global__ __launch_bounds__(256) void k_gemm_dual(
    const float* __restrict__ A, const __half* __restrict__ Bt1, const __half* __restrict__ Bt2,
    const float* __restrict__ bias2, const float* __restrict__ dis,
    __half* __restrict__ C1, __half* __restrict__ C2, int M, int K)
{
    int tid = threadIdx.x;
    int wv = tid >> 6, lane = tid & 63;
    int ln15 = lane & 15, quad = lane >> 4;
    int m0 = blockIdx.x * 64;
    int n0 = wv * 32;
    f32x4 acc1[4][2], acc2[4][2];
#pragma unroll
    for (int mt = 0; mt < 4; ++mt)
#pragma unroll
        for (int nt = 0; nt < 2; ++nt) {
            acc1[mt][nt] = (f32x4){0.f, 0.f, 0.f, 0.f};
            acc2[mt][nt] = (f32x4){0.f, 0.f, 0.f, 0.f};
        }
    int rowm[4];
#pragma unroll
    for (int mt = 0; mt < 4; ++mt) {
        int r = m0 + mt * 16 + ln15;
        rowm[mt] = r < M ? r : M - 1;
    }
    for (int kc = 0; kc < K; kc += 32) {
        f16x8 af[4], bf1[2], bf2[2];
#pragma unroll
        for (int mt = 0; mt < 4; ++mt) {
            const float* ap = &A[(size_t)rowm[mt] * K + kc + quad * 8];
            float4 u0 = *(const float4*)ap, u1 = *(const float4*)(ap + 4);
            af[mt][0] = (_Float16)u0.x; af[mt][1] = (_Float16)u0.y;
            af[mt][2] = (_Float16)u0.z; af[mt][3] = (_Float16)u0.w;
            af[mt][4] = (_Float16)u1.x; af[mt][5] = (_Float16)u1.y;
            af[mt][6] = (_Float16)u1.z; af[mt][7] = (_Float16)u1.w;
        }
#pragma unroll
        for (int nt = 0; nt < 2; ++nt) {
            bf1[nt] = *(const f16x8*)&Bt1[(size_t)(n0 + nt * 16 + ln15) * K + kc + quad * 8];
            bf2[nt] = *(const f16x8*)&Bt2[(size_t)(n0 + nt * 16 + ln15) * K + kc + quad * 8];
        }
#pragma unroll
        for (int mt = 0; mt < 4; ++mt)
#pragma unroll
            for (int nt = 0; nt < 2; ++nt) {
                acc1[mt][nt] = __builtin_amdgcn_mfma_f32_16x16x32_f16(af[mt], bf1[nt], acc1[mt][nt], 0, 0, 0);
                acc2[mt][nt] = __builtin_amdgcn_mfma_f32_16x16x32_f16(af[mt], bf2[nt], acc2[mt][nt], 0, 0, 0);
            }
    }
#pragma unroll
    for (int nt = 0; nt < 2; ++nt) {
        int col = n0 + nt * 16 + ln15;
        float bv2 = bias2[col];
#pragma unroll
        for (int mt = 0; mt < 4; ++mt) {
#pragma unroll
            for (int r = 0; r < 4; ++r) {
                int row = m0 + mt * 16 + quad * 4 + r;
                if (row < M) {
                    C1[(size_t)row * 128 + col] = __float2half(acc1[mt][nt][r] * dis[row]);
                    C2[(size_t)row * 128 + col] = __float2half(acc2[mt][nt][r] + bv2);
                }
            }
        }
    }
}

// ---------------------------------------------------------------- aggregate + bias + LN + residual + relu (f16 pk-fma)
// hw rows are pre-scaled by dis[src]; raw weights in epack; dst scale applied once at epilogue.
__global__ __launch_bounds__(256) void k_agg_ln(
    const __half* __restrict__ hw, const float* __restrict__ dis,
    const int* __restrict__ cnt, const unsigned* __restrict__ epack,
    const float* __restrict__ cb, const float* __restrict__ gam,
    const float* __restrict__ bet, const __half* __restrict__ res,
    __half* __restrict__ out, int n)
{
    int wv = threadIdx.x >> 6;
    int lane = threadIdx.x & 63;
    int i = blockIdx.x * 4 + wv;
    if (i >= n) return;
    float di = dis[i];
    __half2 acca = *(const __half2*)&hw[(size_t)i * HH + lane * 2];  // self-loop, weight 1
    __half2 accb = __halves2half2(__float2half(0.0f), __float2half(0.0f));
    int cn = cnt[i];
    const unsigned* ebase = &epack[(size_t)i * MAXD];    // 256B-aligned per node
    int k = 0;
    for (; k + 8 <= cn; k += 8) {
        uint4 q0 = *(const uint4*)&ebase[k];      // 4 edges
        uint4 q1 = *(const uint4*)&ebase[k + 4];  // 4 edges
        __half2 v0 = *(const __half2*)&hw[(size_t)(q0.x >> 15) * HH + lane * 2];
        __half2 v1 = *(const __half2*)&hw[(size_t)(q0.y >> 15) * HH + lane * 2];
        __half2 v2 = *(const __half2*)&hw[(size_t)(q0.z >> 15) * HH + lane * 2];
        __half2 v3 = *(const __half2*)&hw[(size_t)(q0.w >> 15) * HH + lane * 2];
        __half2 v4 = *(const __half2*)&hw[(size_t)(q1.x >> 15) * HH + lane * 2];
        __half2 v5 = *(const __half2*)&hw[(size_t)(q1.y >> 15) * HH + lane * 2];
        __half2 v6 = *(const __half2*)&hw[(size_t)(q1.z >> 15) * HH + lane * 2];
        __half2 v7 = *(const __half2*)&hw[(size_t)(q1.w >> 15) * HH + lane * 2];
        acca = __hfma2(v0, unpack_w_h2(q0.x), acca);
        accb = __hfma2(v4, unpack_w_h2(q1.x), accb);
        acca = __hfma2(v1, unpack_w_h2(q0.y), acca);
        accb = __hfma2(v5, unpack_w_h2(q1.y), accb);
        acca = __hfma2(v2, unpack_w_h2(q0.z), acca);
        accb = __hfma2(v6, unpack_w_h2(q1.z), accb);
        acca = __hfma2(v3, unpack_w_h2(q0.w), acca);
        accb = __hfma2(v7, unpack_w_h2(q1.w), accb);
    }
    for (; k < cn; ++k) {
        unsigned e = ebase[k];
        __half2 v = *(const __half2*)&hw[(size_t)(e >> 15) * HH + lane * 2];
        acca = __hfma2(v, unpack_w_h2(e), acca);
    }
    __half2 acc = __hadd2(acca, accb);
    float2 af = __half22float2(acc);
    float2 cbv = *(const float2*)&cb[lane * 2];
    af.x = fmaf(di, af.x, cbv.x);          // dst-side normalization + conv bias
    af.y = fmaf(di, af.y, cbv.y);
    // LayerNorm over 128 via wave reduction
    float s1 = af.x + af.y;
    float s2 = af.x * af.x + af.y * af.y;
#pragma unroll
    for (int o = 32; o > 0; o >>= 1) {
        s1 += __shfl_xor(s1, o, 64);
        s2 += __shfl_xor(s2, o, 64);
    }
    float mean = s1 * (1.0f / HH);
    float var = fmaxf(s2 * (1.0f / HH) - mean * mean, 0.0f);
    float rstd = rsqrtf(var + 1e-5f);
    float2 gv = *(const float2*)&gam[lane * 2];
    float2 bv = *(const float2*)&bet[lane * 2];
    float2 rv = __half22float2(*(const __half2*)&res[(size_t)i * HH + lane * 2]);
    float hx = fmaxf(fmaf(gv.x, (af.x - mean) * rstd, bv.x) + rv.x, 0.0f);
    float hy = fmaxf(fmaf(gv.y, (af.y - mean) * rstd, bv.y) + rv.y, 0.0f);
    *(__half2*)&out[(size_t)i * HH + lane * 2] = __floats2half2_rn(hx, hy);
}

// ---------------------------------------------------------------- fused mean/max pool + head (per graph)
__global__ __launch_bounds__(512) void k_pool_head(
    const __half* __restrict__ l0, const __half* __restrict__ l1,
    const __half* __restrict__ l2, const __half* __restrict__ l3,
    const int* __restrict__ batch,
    const float* __restrict__ hW1, const float* __restrict__ hb1,
    const float* __restrict__ hW2, const float* __restrict__ hb2,
    float* __restrict__ out, int n)
{
    __shared__ float ssum[8][128];
    __shared__ float smax[8][128];
    __shared__ __align__(16) float sg[256];
    __shared__ __align__(16) float sh[128];
    int g = blockIdx.x, tid = threadIdx.x;
    int grp = tid >> 6, lane = tid & 63;
    int lo = 0, hi = n;
    while (lo < hi) { int m = (lo + hi) >> 1; if (batch[m] < g) lo = m + 1; else hi = m; }
    int start = lo;
    lo = start; hi = n;
    while (lo < hi) { int m = (lo + hi) >> 1; if (batch[m] < g + 1) lo = m + 1; else hi = m; }
    int end = lo;
    float sx = 0.0f, sy = 0.0f, mx = -INFINITY, my = -INFINITY;
    for (int nd = start + grp; nd < end; nd += 8) {
        size_t off = (size_t)nd * HH + lane * 2;
        float2 v0 = __half22float2(*(const __half2*)&l0[off]);
        float2 v1 = __half22float2(*(const __half2*)&l1[off]);
        float2 v2 = __half22float2(*(const __half2*)&l2[off]);
        float2 v3 = __half22float2(*(const __half2*)&l3[off]);
        float vx = (v0.x + v1.x + v2.x + v3.x) * 0.25f;
        float vy = (v0.y + v1.y + v2.y + v3.y) * 0.25f;
        sx += vx; sy += vy;
        mx = fmaxf(mx, vx); my = fmaxf(my, vy);
    }
    ssum[grp][lane * 2] = sx; ssum[grp][lane * 2 + 1] = sy;
    smax[grp][lane * 2] = mx; smax[grp][lane * 2 + 1] = my;
    __syncthreads();
    if (tid < 128) {
        float s = 0.0f, m = -INFINITY;
#pragma unroll
        for (int j = 0; j < 8; ++j) {
            s += ssum[j][tid];
            m = fmaxf(m, smax[j][tid]);
        }
        int cntg = end - start;
        sg[tid] = s / fmaxf((float)cntg, 1.0f);
        sg[128 + tid] = (cntg > 0) ? m : 0.0f;
    }
    __syncthreads();
    if (tid < 128) {
        float h = hb1[tid];
        for (int k = 0; k < 256; ++k) h = fmaf(sg[k], hW1[(size_t)k * 128 + tid], h);
        sh[tid] = fmaxf(h, 0.0f);
    }
    __syncthreads();
    if (tid < 100) {
        float o = hb2[tid];
        for (int k = 0; k < 128; ++k) o = fmaf(sh[k], hW2[(size_t)k * 100 + tid], o);
        out[(size_t)g * 100 + tid] = o;
    }
}

// ---------------------------------------------------------------- launch
extern "C" void kernel_launch(void* const* d_in, const int* in_sizes, int n_in,
                              void* d_out, int out_size, void* d_ws, size_t ws_size,
                              hipStream_t stream) {
    const float* x     = (const float*)d_in[0];
    const int*   ei    = (const int*)d_in[1];
    const int*   batch = (const int*)d_in[2];
    const float* ea    = (const float*)d_in[3];
    const float* eeW1  = (const float*)d_in[4];
    const float* eeb1  = (const float*)d_in[5];
    const float* eeW2  = (const float*)d_in[6];
    const float* eeb2  = (const float*)d_in[7];
    const float* W[4]  = {(const float*)d_in[8], (const float*)d_in[10], (const float*)d_in[12], (const float*)d_in[14]};
    const float* cb[4] = {(const float*)d_in[9], (const float*)d_in[11], (const float*)d_in[13], (const float*)d_in[15]};
    const float* gm[4] = {(const float*)d_in[16], (const float*)d_in[18], (const float*)d_in[20], (const float*)d_in[22]};
    const float* be[4] = {(const float*)d_in[17], (const float*)d_in[19], (const float*)d_in[21], (const float*)d_in[23]};
    const float* resW  = (const float*)d_in[24];
    const float* resb  = (const float*)d_in[25];
    const float* hW1   = (const float*)d_in[26];
    const float* hb1   = (const float*)d_in[27];
    const float* hW2   = (const float*)d_in[28];
    const float* hb2   = (const float*)d_in[29];
    float* out = (float*)d_out;

    // workspace layout (~175 MB)
    char* w = (char*)d_ws;
    auto alloc = [&](size_t bytes) { void* p = w; w += (bytes + 255) & ~(size_t)255; return p; };
    __half*   ew     = (__half*)  alloc((size_t)EE * 2);                 //  3.2 MB
    float*    dis    = (float*)   alloc((size_t)NN * 4);                 //  0.4 MB
    int*      cnt    = (int*)     alloc((size_t)NN * 4);                 //  0.4 MB
    int*      cntB   = (int*)     alloc((size_t)NBUK * 4);               //  0.8 KB
    uint2*    barr   = (uint2*)   alloc((size_t)NBUK * CAPB * 8);        // 16.1 MB bucket arrays
    unsigned* epack  = (unsigned*)alloc((size_t)(NN * MAXD + 64) * 4);   // 25.6 MB packed CSR (+overread pad)
    __half*   hw     = (__half*)  alloc((size_t)NN * HH * 2);            // 25.6 MB
    __half*   lout[4];
    for (int i = 0; i < 4; ++i) lout[i] = (__half*)alloc((size_t)NN * HH * 2);  // 4 x 25.6 MB
    __half*   wt0    = (__half*)  alloc((size_t)INC * HH * 2);
    __half*   wtR    = (__half*)  alloc((size_t)INC * HH * 2);
    __half*   wt1    = (__half*)  alloc((size_t)HH * HH * 2);
    __half*   wt2    = (__half*)  alloc((size_t)HH * HH * 2);
    __half*   wt3    = (__half*)  alloc((size_t)HH * HH * 2);
    __bf16*   w1f    = (__bf16*)  alloc((size_t)8 * 64 * 8 * 2);         // 8 KB MFMA B-frags for edge MLP
    __half*   wtc[4] = {wt0, wt1, wt2, wt3};
    __half*   res0   = lout[1];   // alias: res0 dead after layer-0 agg; lout[1] written at layer-1 agg

    int nblkEdge = EE / 128;                 // 12500
    int nblkSplit = (EE + EB - 1) / EB;      // 391
    int nblkGemm = (NN + 63) / 64;           // 1563

    k_prep<<<289, 512, 0, stream>>>(W[0], resW, W[1], W[2], W[3], eeW1,
                                    wt0, wtR, wt1, wt2, wt3, w1f, cntB);
    k_edge_mlp_mfma<<<nblkEdge, 256, 0, stream>>>(ea, w1f, eeb1, eeW2, eeb2, ew);
    k_split<<<nblkSplit, 256, 0, stream>>>(ei, ew, cntB, barr);
    k_build<<<NBUK, 256, 0, stream>>>(cntB, barr, epack, cnt, dis);

    // layer 0 (K=96, fp32 A): hw = dis .* (x@W0); res0 = x@res_W + res_b  (one pass over x)
    k_gemm_dual<<<nblkGemm, 256, 0, stream>>>(x, wt0, wtR, resb, dis, hw, res0, NN, INC);
    k_agg_ln<<<(NN + 3) / 4, 256, 0, stream>>>(hw, dis, cnt, epack,
                                               cb[0], gm[0], be[0], res0, lout[0], NN);
    // layers 1..3
    for (int l = 1; l < 4; ++l) {
        k_gemm_f16<<<nblkGemm, 256, 0, stream>>>(lout[l - 1], wtc[l], dis, hw, NN, HH);
        k_agg_ln<<<(NN + 3) / 4, 256, 0, stream>>>(hw, dis, cnt, epack,
                                                   cb[l], gm[l], be[l], lout[l - 1], lout[l], NN);
    }

    k_pool_head<<<GB, 512, 0, stream>>>(lout[0], lout[1], lout[2], lout[3], batch,
                                        hW1, hb1, hW2, hb2, out, NN);
}